// Round 1
// baseline (236.132 us; speedup 1.0000x reference)
//
#include <hip/hip_runtime.h>
#include <math.h>

// Problem constants (from setup_inputs)
#define B_ 4
#define V_ 6
#define C_ 256
#define Q_ 2048
#define KP_ 4
#define H0_ 64
#define W0_ 176
#define H1_ 32
#define W1_ 88
#define RADIUS_ 2.0f

#define F0_ELEMS ((size_t)B_ * V_ * C_ * H0_ * W0_)   // 69,206,016
#define F1_ELEMS ((size_t)B_ * V_ * C_ * H1_ * W1_)   // 17,301,504

// ---------------------------------------------------------------------------
// Transpose [BV, C, HW] -> [BV, HW, C], 64x64 tiles, float4 both directions.
// ---------------------------------------------------------------------------
__global__ __launch_bounds__(256) void transpose_chw_hwc(
    const float* __restrict__ src, float* __restrict__ dst, int HW) {
  __shared__ float tile[64][68];   // +4 pad keeps float4 alignment, breaks stride
  const int bv = blockIdx.z;
  const int p0 = blockIdx.x * 64;  // HW tile origin
  const int c0 = blockIdx.y * 64;  // C tile origin
  const size_t base = (size_t)bv * C_ * HW;
  const int tid = threadIdx.x;

  // Read: coalesced along HW
  {
    const int px4 = (tid & 15) * 4;
    const int crow = tid >> 4;      // 0..15
    for (int j = 0; j < 64; j += 16) {
      const float4 v = *reinterpret_cast<const float4*>(
          src + base + (size_t)(c0 + crow + j) * HW + p0 + px4);
      *reinterpret_cast<float4*>(&tile[crow + j][px4]) = v;
    }
  }
  __syncthreads();
  // Write: coalesced along C
  {
    const int cx4 = (tid & 15) * 4;
    const int prow = tid >> 4;
    for (int j = 0; j < 64; j += 16) {
      float4 v;
      v.x = tile[cx4 + 0][prow + j];
      v.y = tile[cx4 + 1][prow + j];
      v.z = tile[cx4 + 2][prow + j];
      v.w = tile[cx4 + 3][prow + j];
      *reinterpret_cast<float4*>(
          dst + base + (size_t)(p0 + prow + j) * C_ + c0 + cx4) = v;
    }
  }
}

// ---------------------------------------------------------------------------
// Bilinear helpers
// ---------------------------------------------------------------------------
__device__ __forceinline__ void fma4(float4& a, float w, const float4 v) {
  a.x = fmaf(w, v.x, a.x);
  a.y = fmaf(w, v.y, a.y);
  a.z = fmaf(w, v.z, a.z);
  a.w = fmaf(w, v.w, a.w);
}

// fm: [HW, C] (transposed). c4: float4 channel index (lane). Matches
// grid_sample(align_corners=True, padding_mode='zeros') semantics of the ref.
__device__ __forceinline__ void bilinear_acc(
    const float* __restrict__ fm, const int W, const int H,
    const float x, const float y, const int c4, float4& acc) {
  const float x0f = floorf(x), y0f = floorf(y);
  const float wx1 = x - x0f, wy1 = y - y0f;
  const float wx0 = 1.f - wx1, wy0 = 1.f - wy1;
  const float x1f = x0f + 1.f, y1f = y0f + 1.f;
  const float Wm1 = (float)(W - 1), Hm1 = (float)(H - 1);
  const bool bx0 = (x0f >= 0.f) && (x0f <= Wm1);
  const bool bx1 = (x1f >= 0.f) && (x1f <= Wm1);
  const bool by0 = (y0f >= 0.f) && (y0f <= Hm1);
  const bool by1 = (y1f >= 0.f) && (y1f <= Hm1);
  if (!((bx0 || bx1) && (by0 || by1))) return;
  // clamp before int conversion (safe for huge/inf coords; unused when OOB)
  const int xi0 = (int)fminf(fmaxf(x0f, 0.f), Wm1);
  const int xi1 = (int)fminf(fmaxf(x1f, 0.f), Wm1);
  const int yi0 = (int)fminf(fmaxf(y0f, 0.f), Hm1);
  const int yi1 = (int)fminf(fmaxf(y1f, 0.f), Hm1);
  const int co = c4 * 4;
  if (bx0 && by0)
    fma4(acc, wx0 * wy0, *reinterpret_cast<const float4*>(
        fm + (size_t)(yi0 * W + xi0) * C_ + co));
  if (bx1 && by0)
    fma4(acc, wx1 * wy0, *reinterpret_cast<const float4*>(
        fm + (size_t)(yi0 * W + xi1) * C_ + co));
  if (bx0 && by1)
    fma4(acc, wx0 * wy1, *reinterpret_cast<const float4*>(
        fm + (size_t)(yi1 * W + xi0) * C_ + co));
  if (bx1 && by1)
    fma4(acc, wx1 * wy1, *reinterpret_cast<const float4*>(
        fm + (size_t)(yi1 * W + xi1) * C_ + co));
}

// ---------------------------------------------------------------------------
// Main sampler: 1 wave per query q. Lanes 0..23 compute the 24 projections
// (v,kp); broadcast via ballot/shfl. Each lane owns 4 channels (float4).
// ---------------------------------------------------------------------------
__global__ __launch_bounds__(256) void sampler_kernel(
    const float* __restrict__ f0t,   // [B,V,H0*W0,C]
    const float* __restrict__ f1t,   // [B,V,H1*W1,C]
    const float* __restrict__ refs,  // [B,Q,3]
    const float* __restrict__ intr,  // [B,V,3,3]
    const float* __restrict__ extr,  // [B,V,4,4]
    float* __restrict__ out)         // [B,Q,C]
{
  const int tid = threadIdx.x;
  const int wave = tid >> 6;
  const int lane = tid & 63;
  const int b = blockIdx.y;
  const int q = blockIdx.x * 4 + wave;

  const float rx = refs[((size_t)b * Q_ + q) * 3 + 0];
  const float ry = refs[((size_t)b * Q_ + q) * 3 + 1];
  const float rz = refs[((size_t)b * Q_ + q) * 3 + 2];

  float xs = 0.f, ys = 0.f;
  bool zvalid = false;
  if (lane < 24) {
    const int v = lane >> 2, kp = lane & 3;
    const float kx = (kp == 1) ? RADIUS_ : ((kp == 3) ? -RADIUS_ : 0.f);
    const float ky = (kp == 2) ? RADIUS_ : 0.f;
    const float px = rx + kx, py = ry + ky, pz = rz;
    const float* E = extr + ((size_t)b * V_ + v) * 16;
    const float cx = E[0] * px + E[1] * py + E[2]  * pz + E[3];
    const float cy = E[4] * px + E[5] * py + E[6]  * pz + E[7];
    const float cz = E[8] * px + E[9] * py + E[10] * pz + E[11];
    const float* K = intr + ((size_t)b * V_ + v) * 9;
    const float uu = K[0] * cx + K[1] * cy + K[2] * cz;
    const float vv = K[3] * cx + K[4] * cy + K[5] * cz;
    const float ww = K[6] * cx + K[7] * cy + K[8] * cz;
    const float zc = fmaxf(ww, 1e-5f);
    xs = uu / zc;
    ys = vv / zc;
    zvalid = (ww > 0.f);
  }
  const unsigned long long vm = __ballot(zvalid) & 0xFFFFFFULL;
  const float cnt = fmaxf((float)__popcll(vm), 1.0f);

  float4 acc0 = {0.f, 0.f, 0.f, 0.f};
  float4 acc1 = {0.f, 0.f, 0.f, 0.f};

  for (int s = 0; s < 24; ++s) {
    if (!((vm >> s) & 1ULL)) continue;
    const float x = __shfl(xs, s);
    const float y = __shfl(ys, s);
    const int v = s >> 2;
    const size_t bv = (size_t)b * V_ + v;
    bilinear_acc(f0t + bv * (size_t)(H0_ * W0_) * C_, W0_, H0_, x, y, lane, acc0);
    bilinear_acc(f1t + bv * (size_t)(H1_ * W1_) * C_, W1_, H1_, x, y, lane, acc1);
  }

  const float inv = 0.5f / cnt;
  float4 o;
  o.x = (acc0.x + acc1.x) * inv;
  o.y = (acc0.y + acc1.y) * inv;
  o.z = (acc0.z + acc1.z) * inv;
  o.w = (acc0.w + acc1.w) * inv;
  *reinterpret_cast<float4*>(out + ((size_t)b * Q_ + q) * C_ + lane * 4) = o;
}

// ---------------------------------------------------------------------------
// Fallback: direct gather from [B,V,C,H,W] (used only if workspace too small)
// ---------------------------------------------------------------------------
__device__ __forceinline__ float bilinear_scalar(
    const float* __restrict__ fm, const int W, const int H,
    const float x, const float y) {
  const float x0f = floorf(x), y0f = floorf(y);
  const float wx1 = x - x0f, wy1 = y - y0f;
  const float wx0 = 1.f - wx1, wy0 = 1.f - wy1;
  const float x1f = x0f + 1.f, y1f = y0f + 1.f;
  const float Wm1 = (float)(W - 1), Hm1 = (float)(H - 1);
  const bool bx0 = (x0f >= 0.f) && (x0f <= Wm1);
  const bool bx1 = (x1f >= 0.f) && (x1f <= Wm1);
  const bool by0 = (y0f >= 0.f) && (y0f <= Hm1);
  const bool by1 = (y1f >= 0.f) && (y1f <= Hm1);
  if (!((bx0 || bx1) && (by0 || by1))) return 0.f;
  const int xi0 = (int)fminf(fmaxf(x0f, 0.f), Wm1);
  const int xi1 = (int)fminf(fmaxf(x1f, 0.f), Wm1);
  const int yi0 = (int)fminf(fmaxf(y0f, 0.f), Hm1);
  const int yi1 = (int)fminf(fmaxf(y1f, 0.f), Hm1);
  float r = 0.f;
  if (bx0 && by0) r = fmaf(wx0 * wy0, fm[yi0 * W + xi0], r);
  if (bx1 && by0) r = fmaf(wx1 * wy0, fm[yi0 * W + xi1], r);
  if (bx0 && by1) r = fmaf(wx0 * wy1, fm[yi1 * W + xi0], r);
  if (bx1 && by1) r = fmaf(wx1 * wy1, fm[yi1 * W + xi1], r);
  return r;
}

__global__ __launch_bounds__(256) void sampler_direct(
    const float* __restrict__ f0, const float* __restrict__ f1,
    const float* __restrict__ refs, const float* __restrict__ intr,
    const float* __restrict__ extr, float* __restrict__ out) {
  __shared__ float sx[24], sy[24], scnt;
  __shared__ unsigned int smask;
  const int tid = threadIdx.x;
  const int b = blockIdx.y, q = blockIdx.x;
  bool zvalid = false;
  if (tid < 24) {
    const int v = tid >> 2, kp = tid & 3;
    const float kx = (kp == 1) ? RADIUS_ : ((kp == 3) ? -RADIUS_ : 0.f);
    const float ky = (kp == 2) ? RADIUS_ : 0.f;
    const float rx = refs[((size_t)b * Q_ + q) * 3 + 0];
    const float ry = refs[((size_t)b * Q_ + q) * 3 + 1];
    const float rz = refs[((size_t)b * Q_ + q) * 3 + 2];
    const float px = rx + kx, py = ry + ky, pz = rz;
    const float* E = extr + ((size_t)b * V_ + v) * 16;
    const float cx = E[0] * px + E[1] * py + E[2]  * pz + E[3];
    const float cy = E[4] * px + E[5] * py + E[6]  * pz + E[7];
    const float cz = E[8] * px + E[9] * py + E[10] * pz + E[11];
    const float* K = intr + ((size_t)b * V_ + v) * 9;
    const float uu = K[0] * cx + K[1] * cy + K[2] * cz;
    const float vv = K[3] * cx + K[4] * cy + K[5] * cz;
    const float ww = K[6] * cx + K[7] * cy + K[8] * cz;
    const float zc = fmaxf(ww, 1e-5f);
    sx[tid] = uu / zc;
    sy[tid] = vv / zc;
    zvalid = (ww > 0.f);
  }
  const unsigned long long m = __ballot(zvalid);
  if (tid == 0) {
    const unsigned int mm = (unsigned int)(m & 0xFFFFFFULL);
    smask = mm;
    scnt = fmaxf((float)__popc(mm), 1.0f);
  }
  __syncthreads();
  const unsigned int mask = smask;
  const float cnt = scnt;
  const int c = tid;
  float a0 = 0.f, a1 = 0.f;
  for (int s = 0; s < 24; ++s) {
    if (!((mask >> s) & 1u)) continue;
    const float x = sx[s], y = sy[s];
    const int v = s >> 2;
    const size_t bv = (size_t)b * V_ + v;
    a0 += bilinear_scalar(f0 + (bv * C_ + c) * (size_t)(H0_ * W0_), W0_, H0_, x, y);
    a1 += bilinear_scalar(f1 + (bv * C_ + c) * (size_t)(H1_ * W1_), W1_, H1_, x, y);
  }
  out[((size_t)b * Q_ + q) * C_ + c] = (a0 + a1) * 0.5f / cnt;
}

// ---------------------------------------------------------------------------
extern "C" void kernel_launch(void* const* d_in, const int* in_sizes, int n_in,
                              void* d_out, int out_size, void* d_ws, size_t ws_size,
                              hipStream_t stream) {
  const float* feat0 = (const float*)d_in[0];
  const float* feat1 = (const float*)d_in[1];
  const float* refs  = (const float*)d_in[2];
  const float* intr  = (const float*)d_in[3];
  const float* extr  = (const float*)d_in[4];
  float* out = (float*)d_out;

  const size_t f0_bytes = F0_ELEMS * sizeof(float);
  const size_t f1_bytes = F1_ELEMS * sizeof(float);

  if (ws_size >= f0_bytes + f1_bytes) {
    float* f0t = (float*)d_ws;
    float* f1t = (float*)((char*)d_ws + f0_bytes);
    transpose_chw_hwc<<<dim3((H0_ * W0_) / 64, C_ / 64, B_ * V_), 256, 0, stream>>>(
        feat0, f0t, H0_ * W0_);
    transpose_chw_hwc<<<dim3((H1_ * W1_) / 64, C_ / 64, B_ * V_), 256, 0, stream>>>(
        feat1, f1t, H1_ * W1_);
    sampler_kernel<<<dim3(Q_ / 4, B_), 256, 0, stream>>>(
        f0t, f1t, refs, intr, extr, out);
  } else {
    sampler_direct<<<dim3(Q_, B_), 256, 0, stream>>>(
        feat0, feat1, refs, intr, extr, out);
  }
}

// Round 3
// 225.863 us; speedup vs baseline: 1.0455x; 1.0455x over previous
//
#include <hip/hip_runtime.h>
#include <math.h>

// Problem constants (from setup_inputs)
#define B_ 4
#define V_ 6
#define C_ 256
#define Q_ 2048
#define KP_ 4
#define H0_ 64
#define W0_ 176
#define H1_ 32
#define W1_ 88
#define RADIUS_ 2.0f

#define HW0_ (H0_ * W0_)   // 11264
#define HW1_ (H1_ * W1_)   // 2816
#define NQ_  (B_ * Q_)     // 8192

#define F0_ELEMS ((size_t)B_ * V_ * C_ * HW0_)   // 69,206,016
#define F1_ELEMS ((size_t)B_ * V_ * C_ * HW1_)   // 17,301,504

#define CCH_ 128           // channels per chunk (2 chunks); 173 MB chunk fits LLC

// tiles of 64 pixels x 64 channels
#define T0_TILES_ (HW0_ / 64 * B_ * V_)   // 176*24 = 4224
#define T1_TILES_ (HW1_ / 64 * B_ * V_)   // 44*24  = 1056

typedef float f4 __attribute__((ext_vector_type(4)));  // clang vector: OK for nontemporal builtins

// ---------------------------------------------------------------------------
// Projection precompute: one thread per (b,q). Writes per-sample pixel coords,
// a 24-bit validity mask, and the pre-folded scale 0.5/cnt.
// ---------------------------------------------------------------------------
__global__ __launch_bounds__(256) void proj_kernel(
    const float* __restrict__ refs,   // [B,Q,3]
    const float* __restrict__ intr,   // [B,V,3,3]
    const float* __restrict__ extr,   // [B,V,4,4]
    float* __restrict__ xs, float* __restrict__ ys,   // [NQ,24]
    unsigned int* __restrict__ masks, float* __restrict__ invs) {
  const int idx = blockIdx.x * 256 + threadIdx.x;   // b*Q + q
  if (idx >= NQ_) return;
  const int b = idx >> 11;
  const float rx = refs[(size_t)idx * 3 + 0];
  const float ry = refs[(size_t)idx * 3 + 1];
  const float rz = refs[(size_t)idx * 3 + 2];
  unsigned int mask = 0;
  const size_t base = (size_t)idx * 24;
  for (int v = 0; v < V_; ++v) {
    const float* E = extr + ((size_t)b * V_ + v) * 16;
    const float* K = intr + ((size_t)b * V_ + v) * 9;
    for (int kp = 0; kp < KP_; ++kp) {
      const float kx = (kp == 1) ? RADIUS_ : ((kp == 3) ? -RADIUS_ : 0.f);
      const float ky = (kp == 2) ? RADIUS_ : 0.f;
      const float px = rx + kx, py = ry + ky, pz = rz;
      const float cx = E[0] * px + E[1] * py + E[2]  * pz + E[3];
      const float cy = E[4] * px + E[5] * py + E[6]  * pz + E[7];
      const float cz = E[8] * px + E[9] * py + E[10] * pz + E[11];
      const float uu = K[0] * cx + K[1] * cy + K[2] * cz;
      const float vv = K[3] * cx + K[4] * cy + K[5] * cz;
      const float ww = K[6] * cx + K[7] * cy + K[8] * cz;
      const float zc = fmaxf(ww, 1e-5f);
      const int s = v * KP_ + kp;
      xs[base + s] = uu / zc;
      ys[base + s] = vv / zc;
      if (ww > 0.f) mask |= (1u << s);
    }
  }
  masks[idx] = mask;
  invs[idx] = 0.5f / fmaxf((float)__popc(mask), 1.0f);
}

// ---------------------------------------------------------------------------
// Chunked transpose: [BV, 64ch-tile, 64px-tile] of CHW -> HWC, both levels in
// one launch. grid.x = T0_TILES_+T1_TILES_, grid.y = CCH_/64. Nontemporal src
// reads keep the freshly-written dst chunk LLC-resident for the sampler.
// ---------------------------------------------------------------------------
__global__ __launch_bounds__(256) void transpose_chunk(
    const float* __restrict__ f0, const float* __restrict__ f1,
    float* __restrict__ f0t, float* __restrict__ f1t, const int c0) {
  __shared__ float tile[64][68];   // +4 keeps float4 alignment, breaks stride
  int bx = blockIdx.x;
  const float* src; float* dst; int HW, bv, ptile;
  if (bx < T0_TILES_) {
    src = f0; dst = f0t; HW = HW0_;
    bv = bx / (HW0_ / 64); ptile = bx % (HW0_ / 64);
  } else {
    bx -= T0_TILES_;
    src = f1; dst = f1t; HW = HW1_;
    bv = bx / (HW1_ / 64); ptile = bx % (HW1_ / 64);
  }
  const int p0 = ptile * 64;
  const int ct0 = c0 + blockIdx.y * 64;
  const size_t sbase = (size_t)bv * C_ * HW;
  const size_t dbase = (size_t)bv * HW * C_;
  const int tid = threadIdx.x;

  {  // read: coalesced along HW
    const int px4 = (tid & 15) * 4;
    const int crow = tid >> 4;      // 0..15
    for (int j = 0; j < 64; j += 16) {
      const f4 v = __builtin_nontemporal_load(
          reinterpret_cast<const f4*>(
              src + sbase + (size_t)(ct0 + crow + j) * HW + p0 + px4));
      *reinterpret_cast<f4*>(&tile[crow + j][px4]) = v;
    }
  }
  __syncthreads();
  {  // write: coalesced along C
    const int cx4 = (tid & 15) * 4;
    const int prow = tid >> 4;
    for (int j = 0; j < 64; j += 16) {
      f4 v;
      v.x = tile[cx4 + 0][prow + j];
      v.y = tile[cx4 + 1][prow + j];
      v.z = tile[cx4 + 2][prow + j];
      v.w = tile[cx4 + 3][prow + j];
      *reinterpret_cast<f4*>(
          dst + dbase + (size_t)(p0 + prow + j) * C_ + ct0 + cx4) = v;
    }
  }
}

// ---------------------------------------------------------------------------
// Bilinear helper on HWC layout (fm already offset to this lane's channels)
// ---------------------------------------------------------------------------
__device__ __forceinline__ void fma4(f4& a, float w, const f4 v) {
  a.x = fmaf(w, v.x, a.x);
  a.y = fmaf(w, v.y, a.y);
  a.z = fmaf(w, v.z, a.z);
  a.w = fmaf(w, v.w, a.w);
}

__device__ __forceinline__ void bilinear_acc(
    const float* __restrict__ fm, const int W, const int H,
    const float x, const float y, f4& acc) {
  const float x0f = floorf(x), y0f = floorf(y);
  const float wx1 = x - x0f, wy1 = y - y0f;
  const float wx0 = 1.f - wx1, wy0 = 1.f - wy1;
  const float x1f = x0f + 1.f, y1f = y0f + 1.f;
  const float Wm1 = (float)(W - 1), Hm1 = (float)(H - 1);
  const bool bx0 = (x0f >= 0.f) && (x0f <= Wm1);
  const bool bx1 = (x1f >= 0.f) && (x1f <= Wm1);
  const bool by0 = (y0f >= 0.f) && (y0f <= Hm1);
  const bool by1 = (y1f >= 0.f) && (y1f <= Hm1);
  if (!((bx0 || bx1) && (by0 || by1))) return;
  const int xi0 = (int)fminf(fmaxf(x0f, 0.f), Wm1);
  const int xi1 = (int)fminf(fmaxf(x1f, 0.f), Wm1);
  const int yi0 = (int)fminf(fmaxf(y0f, 0.f), Hm1);
  const int yi1 = (int)fminf(fmaxf(y1f, 0.f), Hm1);
  if (bx0 && by0)
    fma4(acc, wx0 * wy0, *reinterpret_cast<const f4*>(
        fm + (size_t)(yi0 * W + xi0) * C_));
  if (bx1 && by0)
    fma4(acc, wx1 * wy0, *reinterpret_cast<const f4*>(
        fm + (size_t)(yi0 * W + xi1) * C_));
  if (bx0 && by1)
    fma4(acc, wx0 * wy1, *reinterpret_cast<const f4*>(
        fm + (size_t)(yi1 * W + xi0) * C_));
  if (bx1 && by1)
    fma4(acc, wx1 * wy1, *reinterpret_cast<const f4*>(
        fm + (size_t)(yi1 * W + xi1) * C_));
}

// ---------------------------------------------------------------------------
// Chunked sampler: wave = one query, lanes = 2 sample-groups x 32 ch-lanes.
// Each ch-lane owns 4 channels (float4) of this 128-channel chunk.
// ---------------------------------------------------------------------------
__global__ __launch_bounds__(256) void sampler_chunk(
    const float* __restrict__ f0t,   // [B,V,HW0,C]
    const float* __restrict__ f1t,   // [B,V,HW1,C]
    const float* __restrict__ xs, const float* __restrict__ ys,
    const unsigned int* __restrict__ masks, const float* __restrict__ invs,
    float* __restrict__ out, const int c0) {
  const int tid = threadIdx.x;
  const int wave = tid >> 6;
  const int lane = tid & 63;
  const int sg = lane >> 5;        // sample group 0/1
  const int cl = lane & 31;        // channel lane: 4 channels each
  const int idx = blockIdx.x * 4 + wave;   // b*Q + q
  const int b = idx >> 11;

  const unsigned int mask = masks[idx];
  const float inv = invs[idx];
  const size_t pbase = (size_t)idx * 24;
  const int coff = c0 + cl * 4;

  f4 acc0 = {0.f, 0.f, 0.f, 0.f};
  f4 acc1 = {0.f, 0.f, 0.f, 0.f};

  for (int i = 0; i < 12; ++i) {
    const int s = i * 2 + sg;
    if ((mask >> s) & 1u) {
      const float x = xs[pbase + s];
      const float y = ys[pbase + s];
      const int v = s >> 2;
      const size_t bv = (size_t)b * V_ + v;
      bilinear_acc(f0t + bv * (size_t)HW0_ * C_ + coff, W0_, H0_, x, y, acc0);
      bilinear_acc(f1t + bv * (size_t)HW1_ * C_ + coff, W1_, H1_, x, y, acc1);
    }
  }

  f4 t = acc0 + acc1;
  t.x += __shfl_xor(t.x, 32);
  t.y += __shfl_xor(t.y, 32);
  t.z += __shfl_xor(t.z, 32);
  t.w += __shfl_xor(t.w, 32);
  if (sg == 0) {
    f4 o = t * inv;
    __builtin_nontemporal_store(
        o, reinterpret_cast<f4*>(out + (size_t)idx * C_ + coff));
  }
}

// ---------------------------------------------------------------------------
// Fallback: direct gather from [B,V,C,H,W] (used only if workspace too small)
// ---------------------------------------------------------------------------
__device__ __forceinline__ float bilinear_scalar(
    const float* __restrict__ fm, const int W, const int H,
    const float x, const float y) {
  const float x0f = floorf(x), y0f = floorf(y);
  const float wx1 = x - x0f, wy1 = y - y0f;
  const float wx0 = 1.f - wx1, wy0 = 1.f - wy1;
  const float x1f = x0f + 1.f, y1f = y0f + 1.f;
  const float Wm1 = (float)(W - 1), Hm1 = (float)(H - 1);
  const bool bx0 = (x0f >= 0.f) && (x0f <= Wm1);
  const bool bx1 = (x1f >= 0.f) && (x1f <= Wm1);
  const bool by0 = (y0f >= 0.f) && (y0f <= Hm1);
  const bool by1 = (y1f >= 0.f) && (y1f <= Hm1);
  if (!((bx0 || bx1) && (by0 || by1))) return 0.f;
  const int xi0 = (int)fminf(fmaxf(x0f, 0.f), Wm1);
  const int xi1 = (int)fminf(fmaxf(x1f, 0.f), Wm1);
  const int yi0 = (int)fminf(fmaxf(y0f, 0.f), Hm1);
  const int yi1 = (int)fminf(fmaxf(y1f, 0.f), Hm1);
  float r = 0.f;
  if (bx0 && by0) r = fmaf(wx0 * wy0, fm[yi0 * W + xi0], r);
  if (bx1 && by0) r = fmaf(wx1 * wy0, fm[yi0 * W + xi1], r);
  if (bx0 && by1) r = fmaf(wx0 * wy1, fm[yi1 * W + xi0], r);
  if (bx1 && by1) r = fmaf(wx1 * wy1, fm[yi1 * W + xi1], r);
  return r;
}

__global__ __launch_bounds__(256) void sampler_direct(
    const float* __restrict__ f0, const float* __restrict__ f1,
    const float* __restrict__ refs, const float* __restrict__ intr,
    const float* __restrict__ extr, float* __restrict__ out) {
  __shared__ float sx[24], sy[24], scnt;
  __shared__ unsigned int smask;
  const int tid = threadIdx.x;
  const int b = blockIdx.y, q = blockIdx.x;
  bool zvalid = false;
  if (tid < 24) {
    const int v = tid >> 2, kp = tid & 3;
    const float kx = (kp == 1) ? RADIUS_ : ((kp == 3) ? -RADIUS_ : 0.f);
    const float ky = (kp == 2) ? RADIUS_ : 0.f;
    const float rx = refs[((size_t)b * Q_ + q) * 3 + 0];
    const float ry = refs[((size_t)b * Q_ + q) * 3 + 1];
    const float rz = refs[((size_t)b * Q_ + q) * 3 + 2];
    const float px = rx + kx, py = ry + ky, pz = rz;
    const float* E = extr + ((size_t)b * V_ + v) * 16;
    const float cx = E[0] * px + E[1] * py + E[2]  * pz + E[3];
    const float cy = E[4] * px + E[5] * py + E[6]  * pz + E[7];
    const float cz = E[8] * px + E[9] * py + E[10] * pz + E[11];
    const float* K = intr + ((size_t)b * V_ + v) * 9;
    const float uu = K[0] * cx + K[1] * cy + K[2] * cz;
    const float vv = K[3] * cx + K[4] * cy + K[5] * cz;
    const float ww = K[6] * cx + K[7] * cy + K[8] * cz;
    const float zc = fmaxf(ww, 1e-5f);
    sx[tid] = uu / zc;
    sy[tid] = vv / zc;
    zvalid = (ww > 0.f);
  }
  const unsigned long long m = __ballot(zvalid);
  if (tid == 0) {
    const unsigned int mm = (unsigned int)(m & 0xFFFFFFULL);
    smask = mm;
    scnt = fmaxf((float)__popc(mm), 1.0f);
  }
  __syncthreads();
  const unsigned int mask = smask;
  const float cnt = scnt;
  const int c = tid;
  float a0 = 0.f, a1 = 0.f;
  for (int s = 0; s < 24; ++s) {
    if (!((mask >> s) & 1u)) continue;
    const float x = sx[s], y = sy[s];
    const int v = s >> 2;
    const size_t bv = (size_t)b * V_ + v;
    a0 += bilinear_scalar(f0 + (bv * C_ + c) * (size_t)HW0_, W0_, H0_, x, y);
    a1 += bilinear_scalar(f1 + (bv * C_ + c) * (size_t)HW1_, W1_, H1_, x, y);
  }
  out[((size_t)b * Q_ + q) * C_ + c] = (a0 + a1) * 0.5f / cnt;
}

// ---------------------------------------------------------------------------
extern "C" void kernel_launch(void* const* d_in, const int* in_sizes, int n_in,
                              void* d_out, int out_size, void* d_ws, size_t ws_size,
                              hipStream_t stream) {
  const float* feat0 = (const float*)d_in[0];
  const float* feat1 = (const float*)d_in[1];
  const float* refs  = (const float*)d_in[2];
  const float* intr  = (const float*)d_in[3];
  const float* extr  = (const float*)d_in[4];
  float* out = (float*)d_out;

  const size_t f0_elems = F0_ELEMS, f1_elems = F1_ELEMS;
  const size_t proj_elems = (size_t)NQ_ * 24;
  const size_t need = (f0_elems + f1_elems + 2 * proj_elems + 2 * NQ_) * 4;

  if (ws_size >= need) {
    float* f0t = (float*)d_ws;
    float* f1t = f0t + f0_elems;
    float* xs  = f1t + f1_elems;
    float* ys  = xs + proj_elems;
    unsigned int* masks = (unsigned int*)(ys + proj_elems);
    float* invs = (float*)(masks + NQ_);

    proj_kernel<<<NQ_ / 256, 256, 0, stream>>>(refs, intr, extr, xs, ys, masks, invs);
    for (int k = 0; k < C_ / CCH_; ++k) {
      const int c0 = k * CCH_;
      transpose_chunk<<<dim3(T0_TILES_ + T1_TILES_, CCH_ / 64), 256, 0, stream>>>(
          feat0, feat1, f0t, f1t, c0);
      sampler_chunk<<<dim3(NQ_ / 4), 256, 0, stream>>>(
          f0t, f1t, xs, ys, masks, invs, out, c0);
    }
  } else {
    sampler_direct<<<dim3(Q_, B_), 256, 0, stream>>>(
        feat0, feat1, refs, intr, extr, out);
  }
}

// Round 4
// 179.503 us; speedup vs baseline: 1.3155x; 1.2583x over previous
//
#include <hip/hip_runtime.h>
#include <math.h>

// Problem constants (from setup_inputs)
#define B_ 4
#define V_ 6
#define C_ 256
#define Q_ 2048
#define KP_ 4
#define H0_ 64
#define W0_ 176
#define H1_ 32
#define W1_ 88
#define RADIUS_ 2.0f

#define HW0_ (H0_ * W0_)   // 11264
#define HW1_ (H1_ * W1_)   // 2816
#define NQ_  (B_ * Q_)     // 8192

#define F0_ELEMS ((size_t)B_ * V_ * C_ * HW0_)   // 69,206,016
#define F1_ELEMS ((size_t)B_ * V_ * C_ * HW1_)   // 17,301,504

// tiles of 64 pixels x 64 channels
#define T0_TILES_ (HW0_ / 64 * B_ * V_)   // 176*24 = 4224
#define T1_TILES_ (HW1_ / 64 * B_ * V_)   // 44*24  = 1056

typedef float f4 __attribute__((ext_vector_type(4)));
typedef unsigned short us4 __attribute__((ext_vector_type(4)));
typedef unsigned short us8 __attribute__((ext_vector_type(8)));

__device__ __forceinline__ unsigned short f2bf(float f) {   // RNE f32->bf16
  const unsigned int x = __float_as_uint(f);
  return (unsigned short)((x + 0x7fffu + ((x >> 16) & 1u)) >> 16);
}
__device__ __forceinline__ float bf2f(unsigned short u) {
  return __uint_as_float((unsigned int)u << 16);
}

// ---------------------------------------------------------------------------
// Projection precompute: one thread per (b,q). Pixel coords (identical for
// both levels: normalize/denormalize cancels), 24-bit z>0 mask, 0.5/cnt.
// ---------------------------------------------------------------------------
__global__ __launch_bounds__(256) void proj_kernel(
    const float* __restrict__ refs,   // [B,Q,3]
    const float* __restrict__ intr,   // [B,V,3,3]
    const float* __restrict__ extr,   // [B,V,4,4]
    float* __restrict__ xs, float* __restrict__ ys,   // [NQ,24]
    unsigned int* __restrict__ masks, float* __restrict__ invs) {
  const int idx = blockIdx.x * 256 + threadIdx.x;   // b*Q + q
  if (idx >= NQ_) return;
  const int b = idx >> 11;
  const float rx = refs[(size_t)idx * 3 + 0];
  const float ry = refs[(size_t)idx * 3 + 1];
  const float rz = refs[(size_t)idx * 3 + 2];
  unsigned int mask = 0;
  const size_t base = (size_t)idx * 24;
  for (int v = 0; v < V_; ++v) {
    const float* E = extr + ((size_t)b * V_ + v) * 16;
    const float* K = intr + ((size_t)b * V_ + v) * 9;
    for (int kp = 0; kp < KP_; ++kp) {
      const float kx = (kp == 1) ? RADIUS_ : ((kp == 3) ? -RADIUS_ : 0.f);
      const float ky = (kp == 2) ? RADIUS_ : 0.f;
      const float px = rx + kx, py = ry + ky, pz = rz;
      const float cx = E[0] * px + E[1] * py + E[2]  * pz + E[3];
      const float cy = E[4] * px + E[5] * py + E[6]  * pz + E[7];
      const float cz = E[8] * px + E[9] * py + E[10] * pz + E[11];
      const float uu = K[0] * cx + K[1] * cy + K[2] * cz;
      const float vv = K[3] * cx + K[4] * cy + K[5] * cz;
      const float ww = K[6] * cx + K[7] * cy + K[8] * cz;
      const float zc = fmaxf(ww, 1e-5f);
      const int s = v * KP_ + kp;
      xs[base + s] = uu / zc;
      ys[base + s] = vv / zc;
      if (ww > 0.f) mask |= (1u << s);
    }
  }
  masks[idx] = mask;
  invs[idx] = 0.5f / fmaxf((float)__popc(mask), 1.0f);
}

// ---------------------------------------------------------------------------
// Transpose CHW f32 -> HWC bf16, both levels in one launch.
// grid.x = T0_TILES_+T1_TILES_ (64px tiles), grid.y = C_/64 (64ch tiles).
// LDS tile stride 69: both ds sides are exactly 2-way (free) conflicts.
// Nontemporal src reads so the streaming src doesn't evict the bf16 dst
// (which must stay LLC-resident for the sampler).
// ---------------------------------------------------------------------------
__global__ __launch_bounds__(256) void transpose_bf16(
    const float* __restrict__ f0, const float* __restrict__ f1,
    unsigned short* __restrict__ f0t, unsigned short* __restrict__ f1t) {
  __shared__ float tile[64][69];
  int bx = blockIdx.x;
  const float* src; unsigned short* dst; int HW, bv, ptile;
  if (bx < T0_TILES_) {
    src = f0; dst = f0t; HW = HW0_;
    bv = bx / (HW0_ / 64); ptile = bx % (HW0_ / 64);
  } else {
    bx -= T0_TILES_;
    src = f1; dst = f1t; HW = HW1_;
    bv = bx / (HW1_ / 64); ptile = bx % (HW1_ / 64);
  }
  const int p0 = ptile * 64;
  const int ct0 = blockIdx.y * 64;
  const size_t sbase = (size_t)bv * C_ * HW;
  const size_t dbase = (size_t)bv * HW * C_;
  const int tid = threadIdx.x;

  {  // read-in: coalesced f32x4 along HW
    const int px4 = (tid & 15) * 4;
    const int crow = tid >> 4;      // 0..15
    for (int j = 0; j < 64; j += 16) {
      const f4 v = __builtin_nontemporal_load(
          reinterpret_cast<const f4*>(
              src + sbase + (size_t)(ct0 + crow + j) * HW + p0 + px4));
      tile[crow + j][px4 + 0] = v.x;
      tile[crow + j][px4 + 1] = v.y;
      tile[crow + j][px4 + 2] = v.z;
      tile[crow + j][px4 + 3] = v.w;
    }
  }
  __syncthreads();
  {  // write-out: us8 (16B) coalesced along C
    const int cx8 = (tid & 7) * 8;
    const int prow = tid >> 3;      // 0..31
    for (int j = 0; j < 64; j += 32) {
      us8 o;
      #pragma unroll
      for (int k = 0; k < 8; ++k) o[k] = f2bf(tile[cx8 + k][prow + j]);
      *reinterpret_cast<us8*>(
          dst + dbase + (size_t)(p0 + prow + j) * C_ + ct0 + cx8) = o;
    }
  }
}

// ---------------------------------------------------------------------------
// Bilinear on bf16 HWC (fm pre-offset to this lane's 4 channels)
// ---------------------------------------------------------------------------
__device__ __forceinline__ void fma_bf4(f4& a, float w, const us4 u) {
  a.x = fmaf(w, bf2f(u.x), a.x);
  a.y = fmaf(w, bf2f(u.y), a.y);
  a.z = fmaf(w, bf2f(u.z), a.z);
  a.w = fmaf(w, bf2f(u.w), a.w);
}

__device__ __forceinline__ void bilinear_acc(
    const unsigned short* __restrict__ fm, const int W, const int H,
    const float x, const float y, f4& acc) {
  const float x0f = floorf(x), y0f = floorf(y);
  const float wx1 = x - x0f, wy1 = y - y0f;
  const float wx0 = 1.f - wx1, wy0 = 1.f - wy1;
  const float x1f = x0f + 1.f, y1f = y0f + 1.f;
  const float Wm1 = (float)(W - 1), Hm1 = (float)(H - 1);
  const bool bx0 = (x0f >= 0.f) && (x0f <= Wm1);
  const bool bx1 = (x1f >= 0.f) && (x1f <= Wm1);
  const bool by0 = (y0f >= 0.f) && (y0f <= Hm1);
  const bool by1 = (y1f >= 0.f) && (y1f <= Hm1);
  if (!((bx0 || bx1) && (by0 || by1))) return;
  const int xi0 = (int)fminf(fmaxf(x0f, 0.f), Wm1);
  const int xi1 = (int)fminf(fmaxf(x1f, 0.f), Wm1);
  const int yi0 = (int)fminf(fmaxf(y0f, 0.f), Hm1);
  const int yi1 = (int)fminf(fmaxf(y1f, 0.f), Hm1);
  if (bx0 && by0)
    fma_bf4(acc, wx0 * wy0, *reinterpret_cast<const us4*>(
        fm + (size_t)(yi0 * W + xi0) * C_));
  if (bx1 && by0)
    fma_bf4(acc, wx1 * wy0, *reinterpret_cast<const us4*>(
        fm + (size_t)(yi0 * W + xi1) * C_));
  if (bx0 && by1)
    fma_bf4(acc, wx0 * wy1, *reinterpret_cast<const us4*>(
        fm + (size_t)(yi1 * W + xi0) * C_));
  if (bx1 && by1)
    fma_bf4(acc, wx1 * wy1, *reinterpret_cast<const us4*>(
        fm + (size_t)(yi1 * W + xi1) * C_));
}

// ---------------------------------------------------------------------------
// Sampler: wave = one query; lane owns 4 channels. All branches wave-uniform.
// ---------------------------------------------------------------------------
__global__ __launch_bounds__(256) void sampler_bf16(
    const unsigned short* __restrict__ f0t,   // [B,V,HW0,C] bf16
    const unsigned short* __restrict__ f1t,   // [B,V,HW1,C] bf16
    const float* __restrict__ xs, const float* __restrict__ ys,
    const unsigned int* __restrict__ masks, const float* __restrict__ invs,
    float* __restrict__ out) {
  const int tid = threadIdx.x;
  const int wave = tid >> 6;
  const int lane = tid & 63;
  const int idx = blockIdx.x * 4 + wave;   // b*Q + q
  const int b = idx >> 11;

  const unsigned int mask = masks[idx];
  const float inv = invs[idx];
  const size_t pbase = (size_t)idx * 24;
  const int c = lane * 4;

  f4 acc0 = {0.f, 0.f, 0.f, 0.f};
  f4 acc1 = {0.f, 0.f, 0.f, 0.f};

  for (int s = 0; s < 24; ++s) {
    if (!((mask >> s) & 1u)) continue;
    const float x = xs[pbase + s];
    const float y = ys[pbase + s];
    const int v = s >> 2;
    const size_t bv = (size_t)b * V_ + v;
    bilinear_acc(f0t + bv * (size_t)HW0_ * C_ + c, W0_, H0_, x, y, acc0);
    bilinear_acc(f1t + bv * (size_t)HW1_ * C_ + c, W1_, H1_, x, y, acc1);
  }

  const f4 o = (acc0 + acc1) * inv;
  __builtin_nontemporal_store(
      o, reinterpret_cast<f4*>(out + (size_t)idx * C_ + c));
}

// ---------------------------------------------------------------------------
// Fallback: direct gather from [B,V,C,H,W] (used only if workspace too small)
// ---------------------------------------------------------------------------
__device__ __forceinline__ float bilinear_scalar(
    const float* __restrict__ fm, const int W, const int H,
    const float x, const float y) {
  const float x0f = floorf(x), y0f = floorf(y);
  const float wx1 = x - x0f, wy1 = y - y0f;
  const float wx0 = 1.f - wx1, wy0 = 1.f - wy1;
  const float x1f = x0f + 1.f, y1f = y0f + 1.f;
  const float Wm1 = (float)(W - 1), Hm1 = (float)(H - 1);
  const bool bx0 = (x0f >= 0.f) && (x0f <= Wm1);
  const bool bx1 = (x1f >= 0.f) && (x1f <= Wm1);
  const bool by0 = (y0f >= 0.f) && (y0f <= Hm1);
  const bool by1 = (y1f >= 0.f) && (y1f <= Hm1);
  if (!((bx0 || bx1) && (by0 || by1))) return 0.f;
  const int xi0 = (int)fminf(fmaxf(x0f, 0.f), Wm1);
  const int xi1 = (int)fminf(fmaxf(x1f, 0.f), Wm1);
  const int yi0 = (int)fminf(fmaxf(y0f, 0.f), Hm1);
  const int yi1 = (int)fminf(fmaxf(y1f, 0.f), Hm1);
  float r = 0.f;
  if (bx0 && by0) r = fmaf(wx0 * wy0, fm[yi0 * W + xi0], r);
  if (bx1 && by0) r = fmaf(wx1 * wy0, fm[yi0 * W + xi1], r);
  if (bx0 && by1) r = fmaf(wx0 * wy1, fm[yi1 * W + xi0], r);
  if (bx1 && by1) r = fmaf(wx1 * wy1, fm[yi1 * W + xi1], r);
  return r;
}

__global__ __launch_bounds__(256) void sampler_direct(
    const float* __restrict__ f0, const float* __restrict__ f1,
    const float* __restrict__ refs, const float* __restrict__ intr,
    const float* __restrict__ extr, float* __restrict__ out) {
  __shared__ float sx[24], sy[24], scnt;
  __shared__ unsigned int smask;
  const int tid = threadIdx.x;
  const int b = blockIdx.y, q = blockIdx.x;
  bool zvalid = false;
  if (tid < 24) {
    const int v = tid >> 2, kp = tid & 3;
    const float kx = (kp == 1) ? RADIUS_ : ((kp == 3) ? -RADIUS_ : 0.f);
    const float ky = (kp == 2) ? RADIUS_ : 0.f;
    const float rx = refs[((size_t)b * Q_ + q) * 3 + 0];
    const float ry = refs[((size_t)b * Q_ + q) * 3 + 1];
    const float rz = refs[((size_t)b * Q_ + q) * 3 + 2];
    const float px = rx + kx, py = ry + ky, pz = rz;
    const float* E = extr + ((size_t)b * V_ + v) * 16;
    const float cx = E[0] * px + E[1] * py + E[2]  * pz + E[3];
    const float cy = E[4] * px + E[5] * py + E[6]  * pz + E[7];
    const float cz = E[8] * px + E[9] * py + E[10] * pz + E[11];
    const float* K = intr + ((size_t)b * V_ + v) * 9;
    const float uu = K[0] * cx + K[1] * cy + K[2] * cz;
    const float vv = K[3] * cx + K[4] * cy + K[5] * cz;
    const float ww = K[6] * cx + K[7] * cy + K[8] * cz;
    const float zc = fmaxf(ww, 1e-5f);
    sx[tid] = uu / zc;
    sy[tid] = vv / zc;
    zvalid = (ww > 0.f);
  }
  const unsigned long long m = __ballot(zvalid);
  if (tid == 0) {
    const unsigned int mm = (unsigned int)(m & 0xFFFFFFULL);
    smask = mm;
    scnt = fmaxf((float)__popc(mm), 1.0f);
  }
  __syncthreads();
  const unsigned int mask = smask;
  const float cnt = scnt;
  const int c = tid;
  float a0 = 0.f, a1 = 0.f;
  for (int s = 0; s < 24; ++s) {
    if (!((mask >> s) & 1u)) continue;
    const float x = sx[s], y = sy[s];
    const int v = s >> 2;
    const size_t bv = (size_t)b * V_ + v;
    a0 += bilinear_scalar(f0 + (bv * C_ + c) * (size_t)HW0_, W0_, H0_, x, y);
    a1 += bilinear_scalar(f1 + (bv * C_ + c) * (size_t)HW1_, W1_, H1_, x, y);
  }
  out[((size_t)b * Q_ + q) * C_ + c] = (a0 + a1) * 0.5f / cnt;
}

// ---------------------------------------------------------------------------
extern "C" void kernel_launch(void* const* d_in, const int* in_sizes, int n_in,
                              void* d_out, int out_size, void* d_ws, size_t ws_size,
                              hipStream_t stream) {
  const float* feat0 = (const float*)d_in[0];
  const float* feat1 = (const float*)d_in[1];
  const float* refs  = (const float*)d_in[2];
  const float* intr  = (const float*)d_in[3];
  const float* extr  = (const float*)d_in[4];
  float* out = (float*)d_out;

  const size_t proj_elems = (size_t)NQ_ * 24;
  const size_t need = F0_ELEMS * 2 + F1_ELEMS * 2          // bf16 copies
                    + (2 * proj_elems + 2 * NQ_) * 4;      // coords + mask + inv

  if (ws_size >= need) {
    unsigned short* f0t = (unsigned short*)d_ws;
    unsigned short* f1t = f0t + F0_ELEMS;
    float* xs  = (float*)(f1t + F1_ELEMS);
    float* ys  = xs + proj_elems;
    unsigned int* masks = (unsigned int*)(ys + proj_elems);
    float* invs = (float*)(masks + NQ_);

    proj_kernel<<<NQ_ / 256, 256, 0, stream>>>(refs, intr, extr, xs, ys, masks, invs);
    transpose_bf16<<<dim3(T0_TILES_ + T1_TILES_, C_ / 64), 256, 0, stream>>>(
        feat0, feat1, f0t, f1t);
    sampler_bf16<<<dim3(NQ_ / 4), 256, 0, stream>>>(
        f0t, f1t, xs, ys, masks, invs, out);
  } else {
    sampler_direct<<<dim3(Q_, B_), 256, 0, stream>>>(
        feat0, feat1, refs, intr, extr, out);
  }
}

// Round 5
// 156.200 us; speedup vs baseline: 1.5117x; 1.1492x over previous
//
#include <hip/hip_runtime.h>
#include <math.h>

// Problem constants (from setup_inputs)
#define B_ 4
#define V_ 6
#define C_ 256
#define Q_ 2048
#define KP_ 4
#define H0_ 64
#define W0_ 176
#define H1_ 32
#define W1_ 88
#define RADIUS_ 2.0f

#define HW0_ (H0_ * W0_)   // 11264
#define HW1_ (H1_ * W1_)   // 2816
#define NQ_  (B_ * Q_)     // 8192

#define F0_ELEMS ((size_t)B_ * V_ * C_ * HW0_)   // 69,206,016
#define F1_ELEMS ((size_t)B_ * V_ * C_ * HW1_)   // 17,301,504

// tiles of 64 pixels x 64 channels
#define T0_TILES_ (HW0_ / 64 * B_ * V_)   // 176*24 = 4224
#define T1_TILES_ (HW1_ / 64 * B_ * V_)   // 44*24  = 1056

typedef float f4 __attribute__((ext_vector_type(4)));
typedef unsigned short us8 __attribute__((ext_vector_type(8)));

__device__ __forceinline__ unsigned short f2bf(float f) {   // RNE f32->bf16
  const unsigned int x = __float_as_uint(f);
  return (unsigned short)((x + 0x7fffu + ((x >> 16) & 1u)) >> 16);
}
__device__ __forceinline__ float bf2f(unsigned short u) {
  return __uint_as_float((unsigned int)u << 16);
}

// ---------------------------------------------------------------------------
// Projection precompute: one thread per (b,q). Pixel coords (identical for
// both levels: normalize/denormalize cancels), interleaved xy, 24-bit z>0
// mask, pre-folded 0.5/cnt.
// ---------------------------------------------------------------------------
__global__ __launch_bounds__(256) void proj_kernel(
    const float* __restrict__ refs,   // [B,Q,3]
    const float* __restrict__ intr,   // [B,V,3,3]
    const float* __restrict__ extr,   // [B,V,4,4]
    float* __restrict__ xy,           // [NQ,24,2]
    unsigned int* __restrict__ masks, float* __restrict__ invs) {
  const int idx = blockIdx.x * 256 + threadIdx.x;   // b*Q + q
  if (idx >= NQ_) return;
  const int b = idx >> 11;
  const float rx = refs[(size_t)idx * 3 + 0];
  const float ry = refs[(size_t)idx * 3 + 1];
  const float rz = refs[(size_t)idx * 3 + 2];
  unsigned int mask = 0;
  const size_t base = (size_t)idx * 48;
  for (int v = 0; v < V_; ++v) {
    const float* E = extr + ((size_t)b * V_ + v) * 16;
    const float* K = intr + ((size_t)b * V_ + v) * 9;
    for (int kp = 0; kp < KP_; ++kp) {
      const float kx = (kp == 1) ? RADIUS_ : ((kp == 3) ? -RADIUS_ : 0.f);
      const float ky = (kp == 2) ? RADIUS_ : 0.f;
      const float px = rx + kx, py = ry + ky, pz = rz;
      const float cx = E[0] * px + E[1] * py + E[2]  * pz + E[3];
      const float cy = E[4] * px + E[5] * py + E[6]  * pz + E[7];
      const float cz = E[8] * px + E[9] * py + E[10] * pz + E[11];
      const float uu = K[0] * cx + K[1] * cy + K[2] * cz;
      const float vv = K[3] * cx + K[4] * cy + K[5] * cz;
      const float ww = K[6] * cx + K[7] * cy + K[8] * cz;
      const float zc = fmaxf(ww, 1e-5f);
      const int s = v * KP_ + kp;
      xy[base + 2 * s]     = uu / zc;
      xy[base + 2 * s + 1] = vv / zc;
      if (ww > 0.f) mask |= (1u << s);
    }
  }
  masks[idx] = mask;
  invs[idx] = 0.5f / fmaxf((float)__popc(mask), 1.0f);
}

// ---------------------------------------------------------------------------
// Transpose CHW f32 -> HWC bf16, both levels in one launch.
// grid.x = T0_TILES_+T1_TILES_ (64px tiles), grid.y = C_/64 (64ch tiles).
// Nontemporal src reads keep the streaming f32 src from evicting the bf16
// dst (which must stay LLC-resident for the sampler).
// ---------------------------------------------------------------------------
__global__ __launch_bounds__(256) void transpose_bf16(
    const float* __restrict__ f0, const float* __restrict__ f1,
    unsigned short* __restrict__ f0t, unsigned short* __restrict__ f1t) {
  __shared__ float tile[64][69];
  int bx = blockIdx.x;
  const float* src; unsigned short* dst; int HW, bv, ptile;
  if (bx < T0_TILES_) {
    src = f0; dst = f0t; HW = HW0_;
    bv = bx / (HW0_ / 64); ptile = bx % (HW0_ / 64);
  } else {
    bx -= T0_TILES_;
    src = f1; dst = f1t; HW = HW1_;
    bv = bx / (HW1_ / 64); ptile = bx % (HW1_ / 64);
  }
  const int p0 = ptile * 64;
  const int ct0 = blockIdx.y * 64;
  const size_t sbase = (size_t)bv * C_ * HW;
  const size_t dbase = (size_t)bv * HW * C_;
  const int tid = threadIdx.x;

  {  // read-in: coalesced f32x4 along HW
    const int px4 = (tid & 15) * 4;
    const int crow = tid >> 4;      // 0..15
    for (int j = 0; j < 64; j += 16) {
      const f4 v = __builtin_nontemporal_load(
          reinterpret_cast<const f4*>(
              src + sbase + (size_t)(ct0 + crow + j) * HW + p0 + px4));
      tile[crow + j][px4 + 0] = v.x;
      tile[crow + j][px4 + 1] = v.y;
      tile[crow + j][px4 + 2] = v.z;
      tile[crow + j][px4 + 3] = v.w;
    }
  }
  __syncthreads();
  {  // write-out: us8 (16B) coalesced along C
    const int cx8 = (tid & 7) * 8;
    const int prow = tid >> 3;      // 0..31
    for (int j = 0; j < 64; j += 32) {
      us8 o;
      #pragma unroll
      for (int k = 0; k < 8; ++k) o[k] = f2bf(tile[cx8 + k][prow + j]);
      *reinterpret_cast<us8*>(
          dst + dbase + (size_t)(p0 + prow + j) * C_ + ct0 + cx8) = o;
    }
  }
}

// ---------------------------------------------------------------------------
// Merged row-pair bilinear: one 16B/lane load covers both x-corners of a row.
// half=lane>>5 selects x0/x1 side; cidx=lane&31 selects 8 channels. Clamped
// per-lane x keeps addresses on real (finite) data; OOB side gets weight 0.
// ---------------------------------------------------------------------------
__device__ __forceinline__ void sample_level(
    const unsigned short* __restrict__ base,   // level base for (b,v), +ce
    const int W, const int H,
    const float x0f, const float y0f,
    const float wx0, const float wx1, const float wy0, const float wy1,
    const int half, float acc[8]) {
  const float Wm1 = (float)(W - 1), Hm1 = (float)(H - 1);
  const float x1f = x0f + 1.f, y1f = y0f + 1.f;
  const bool bx0 = (x0f >= 0.f) && (x0f <= Wm1);
  const bool bx1 = (x1f >= 0.f) && (x1f <= Wm1);
  const bool by0 = (y0f >= 0.f) && (y0f <= Hm1);
  const bool by1 = (y1f >= 0.f) && (y1f <= Hm1);
  if (!((bx0 || bx1) && (by0 || by1))) return;
  const int xi0 = (int)fminf(fmaxf(x0f, 0.f), Wm1);
  const int xi1 = (int)fminf(fmaxf(x1f, 0.f), Wm1);
  const int xh = half ? xi1 : xi0;
  const float wxh = half ? (bx1 ? wx1 : 0.f) : (bx0 ? wx0 : 0.f);
  if (by0) {
    const int yi0 = (int)fminf(fmaxf(y0f, 0.f), Hm1);
    const us8 u = *reinterpret_cast<const us8*>(base + (size_t)(yi0 * W + xh) * C_);
    const float w = wxh * wy0;
    #pragma unroll
    for (int k = 0; k < 8; ++k) acc[k] = fmaf(w, bf2f(u[k]), acc[k]);
  }
  if (by1) {
    const int yi1 = (int)fminf(fmaxf(y1f, 0.f), Hm1);
    const us8 u = *reinterpret_cast<const us8*>(base + (size_t)(yi1 * W + xh) * C_);
    const float w = wxh * wy1;
    #pragma unroll
    for (int k = 0; k < 8; ++k) acc[k] = fmaf(w, bf2f(u[k]), acc[k]);
  }
}

// ---------------------------------------------------------------------------
// Sampler: wave = one query. 96 VMEM requests/query (vs 192 corner reads).
// ---------------------------------------------------------------------------
__global__ __launch_bounds__(256) void sampler_bf16(
    const unsigned short* __restrict__ f0t,   // [B,V,HW0,C] bf16
    const unsigned short* __restrict__ f1t,   // [B,V,HW1,C] bf16
    const float* __restrict__ xy,             // [NQ,24,2]
    const unsigned int* __restrict__ masks, const float* __restrict__ invs,
    float* __restrict__ out) {
  const int tid = threadIdx.x;
  const int wave = tid >> 6;
  const int lane = tid & 63;
  const int half = lane >> 5;
  const int cidx = lane & 31;      // 8 channels: 8*cidx .. 8*cidx+7
  const int idx = blockIdx.x * 4 + wave;   // b*Q + q
  const int b = idx >> 11;

  const unsigned int mask = masks[idx];
  const float inv = invs[idx];
  const float* pxy = xy + (size_t)idx * 48;
  const int ce = cidx * 8;

  const unsigned short* F0 = f0t + (size_t)b * V_ * HW0_ * C_ + ce;
  const unsigned short* F1 = f1t + (size_t)b * V_ * HW1_ * C_ + ce;

  float acc[8] = {0.f, 0.f, 0.f, 0.f, 0.f, 0.f, 0.f, 0.f};

  for (int s = 0; s < 24; ++s) {
    if (!((mask >> s) & 1u)) continue;
    const float x = pxy[2 * s], y = pxy[2 * s + 1];
    const float x0f = floorf(x), y0f = floorf(y);
    const float wx1 = x - x0f, wy1 = y - y0f;
    const float wx0 = 1.f - wx1, wy0 = 1.f - wy1;
    const int v = s >> 2;
    sample_level(F0 + (size_t)v * HW0_ * C_, W0_, H0_,
                 x0f, y0f, wx0, wx1, wy0, wy1, half, acc);
    sample_level(F1 + (size_t)v * HW1_ * C_, W1_, H1_,
                 x0f, y0f, wx0, wx1, wy0, wy1, half, acc);
  }

  // cross-half reduce: lane i and i+32 hold the same 8 channels
  #pragma unroll
  for (int k = 0; k < 8; ++k) acc[k] += __shfl_xor(acc[k], 32);

  // store: half 0 writes ch [8c,8c+4), half 1 writes [8c+4,8c+8)
  f4 o;
  const int ko = half * 4;
  o.x = acc[ko + 0] * inv;
  o.y = acc[ko + 1] * inv;
  o.z = acc[ko + 2] * inv;
  o.w = acc[ko + 3] * inv;
  __builtin_nontemporal_store(
      o, reinterpret_cast<f4*>(out + (size_t)idx * C_ + ce + ko));
}

// ---------------------------------------------------------------------------
// Fallback: direct gather from [B,V,C,H,W] (used only if workspace too small)
// ---------------------------------------------------------------------------
__device__ __forceinline__ float bilinear_scalar(
    const float* __restrict__ fm, const int W, const int H,
    const float x, const float y) {
  const float x0f = floorf(x), y0f = floorf(y);
  const float wx1 = x - x0f, wy1 = y - y0f;
  const float wx0 = 1.f - wx1, wy0 = 1.f - wy1;
  const float x1f = x0f + 1.f, y1f = y0f + 1.f;
  const float Wm1 = (float)(W - 1), Hm1 = (float)(H - 1);
  const bool bx0 = (x0f >= 0.f) && (x0f <= Wm1);
  const bool bx1 = (x1f >= 0.f) && (x1f <= Wm1);
  const bool by0 = (y0f >= 0.f) && (y0f <= Hm1);
  const bool by1 = (y1f >= 0.f) && (y1f <= Hm1);
  if (!((bx0 || bx1) && (by0 || by1))) return 0.f;
  const int xi0 = (int)fminf(fmaxf(x0f, 0.f), Wm1);
  const int xi1 = (int)fminf(fmaxf(x1f, 0.f), Wm1);
  const int yi0 = (int)fminf(fmaxf(y0f, 0.f), Hm1);
  const int yi1 = (int)fminf(fmaxf(y1f, 0.f), Hm1);
  float r = 0.f;
  if (bx0 && by0) r = fmaf(wx0 * wy0, fm[yi0 * W + xi0], r);
  if (bx1 && by0) r = fmaf(wx1 * wy0, fm[yi0 * W + xi1], r);
  if (bx0 && by1) r = fmaf(wx0 * wy1, fm[yi1 * W + xi0], r);
  if (bx1 && by1) r = fmaf(wx1 * wy1, fm[yi1 * W + xi1], r);
  return r;
}

__global__ __launch_bounds__(256) void sampler_direct(
    const float* __restrict__ f0, const float* __restrict__ f1,
    const float* __restrict__ refs, const float* __restrict__ intr,
    const float* __restrict__ extr, float* __restrict__ out) {
  __shared__ float sx[24], sy[24], scnt;
  __shared__ unsigned int smask;
  const int tid = threadIdx.x;
  const int b = blockIdx.y, q = blockIdx.x;
  bool zvalid = false;
  if (tid < 24) {
    const int v = tid >> 2, kp = tid & 3;
    const float kx = (kp == 1) ? RADIUS_ : ((kp == 3) ? -RADIUS_ : 0.f);
    const float ky = (kp == 2) ? RADIUS_ : 0.f;
    const float rx = refs[((size_t)b * Q_ + q) * 3 + 0];
    const float ry = refs[((size_t)b * Q_ + q) * 3 + 1];
    const float rz = refs[((size_t)b * Q_ + q) * 3 + 2];
    const float px = rx + kx, py = ry + ky, pz = rz;
    const float* E = extr + ((size_t)b * V_ + v) * 16;
    const float cx = E[0] * px + E[1] * py + E[2]  * pz + E[3];
    const float cy = E[4] * px + E[5] * py + E[6]  * pz + E[7];
    const float cz = E[8] * px + E[9] * py + E[10] * pz + E[11];
    const float* K = intr + ((size_t)b * V_ + v) * 9;
    const float uu = K[0] * cx + K[1] * cy + K[2] * cz;
    const float vv = K[3] * cx + K[4] * cy + K[5] * cz;
    const float ww = K[6] * cx + K[7] * cy + K[8] * cz;
    const float zc = fmaxf(ww, 1e-5f);
    sx[tid] = uu / zc;
    sy[tid] = vv / zc;
    zvalid = (ww > 0.f);
  }
  const unsigned long long m = __ballot(zvalid);
  if (tid == 0) {
    const unsigned int mm = (unsigned int)(m & 0xFFFFFFULL);
    smask = mm;
    scnt = fmaxf((float)__popc(mm), 1.0f);
  }
  __syncthreads();
  const unsigned int mask = smask;
  const float cnt = scnt;
  const int c = tid;
  float a0 = 0.f, a1 = 0.f;
  for (int s = 0; s < 24; ++s) {
    if (!((mask >> s) & 1u)) continue;
    const float x = sx[s], y = sy[s];
    const int v = s >> 2;
    const size_t bv = (size_t)b * V_ + v;
    a0 += bilinear_scalar(f0 + (bv * C_ + c) * (size_t)HW0_, W0_, H0_, x, y);
    a1 += bilinear_scalar(f1 + (bv * C_ + c) * (size_t)HW1_, W1_, H1_, x, y);
  }
  out[((size_t)b * Q_ + q) * C_ + c] = (a0 + a1) * 0.5f / cnt;
}

// ---------------------------------------------------------------------------
extern "C" void kernel_launch(void* const* d_in, const int* in_sizes, int n_in,
                              void* d_out, int out_size, void* d_ws, size_t ws_size,
                              hipStream_t stream) {
  const float* feat0 = (const float*)d_in[0];
  const float* feat1 = (const float*)d_in[1];
  const float* refs  = (const float*)d_in[2];
  const float* intr  = (const float*)d_in[3];
  const float* extr  = (const float*)d_in[4];
  float* out = (float*)d_out;

  const size_t need = F0_ELEMS * 2 + F1_ELEMS * 2          // bf16 copies
                    + ((size_t)NQ_ * 48 + 2 * NQ_) * 4;    // xy + mask + inv

  if (ws_size >= need) {
    unsigned short* f0t = (unsigned short*)d_ws;
    unsigned short* f1t = f0t + F0_ELEMS;
    float* xy = (float*)(f1t + F1_ELEMS);
    unsigned int* masks = (unsigned int*)(xy + (size_t)NQ_ * 48);
    float* invs = (float*)(masks + NQ_);

    proj_kernel<<<NQ_ / 256, 256, 0, stream>>>(refs, intr, extr, xy, masks, invs);
    transpose_bf16<<<dim3(T0_TILES_ + T1_TILES_, C_ / 64), 256, 0, stream>>>(
        feat0, feat1, f0t, f1t);
    sampler_bf16<<<dim3(NQ_ / 4), 256, 0, stream>>>(
        f0t, f1t, xy, masks, invs, out);
  } else {
    sampler_direct<<<dim3(Q_, B_), 256, 0, stream>>>(
        feat0, feat1, refs, intr, extr, out);
  }
}

// Round 6
// 154.764 us; speedup vs baseline: 1.5257x; 1.0093x over previous
//
#include <hip/hip_runtime.h>
#include <math.h>

// Problem constants (from setup_inputs)
#define B_ 4
#define V_ 6
#define C_ 256
#define Q_ 2048
#define KP_ 4
#define H0_ 64
#define W0_ 176
#define H1_ 32
#define W1_ 88
#define RADIUS_ 2.0f

#define HW0_ (H0_ * W0_)   // 11264
#define HW1_ (H1_ * W1_)   // 2816
#define NQ_  (B_ * Q_)     // 8192

#define F0_ELEMS ((size_t)B_ * V_ * C_ * HW0_)   // 69,206,016
#define F1_ELEMS ((size_t)B_ * V_ * C_ * HW1_)   // 17,301,504

// tiles of 64 pixels x 64 channels
#define T0_TILES_ (HW0_ / 64 * B_ * V_)   // 176*24 = 4224
#define T1_TILES_ (HW1_ / 64 * B_ * V_)   // 44*24  = 1056

typedef float f4 __attribute__((ext_vector_type(4)));
typedef unsigned short us8 __attribute__((ext_vector_type(8)));

__device__ __forceinline__ unsigned short f2bf(float f) {   // RNE f32->bf16
  const unsigned int x = __float_as_uint(f);
  return (unsigned short)((x + 0x7fffu + ((x >> 16) & 1u)) >> 16);
}
__device__ __forceinline__ float bf2f(unsigned short u) {
  return __uint_as_float((unsigned int)u << 16);
}

// ---------------------------------------------------------------------------
// Projection precompute: one thread per (b,q). Pixel coords (identical for
// both levels: normalize/denormalize cancels), interleaved xy, 24-bit z>0
// mask, pre-folded 0.5/cnt.
// ---------------------------------------------------------------------------
__global__ __launch_bounds__(256) void proj_kernel(
    const float* __restrict__ refs,   // [B,Q,3]
    const float* __restrict__ intr,   // [B,V,3,3]
    const float* __restrict__ extr,   // [B,V,4,4]
    float* __restrict__ xy,           // [NQ,24,2]
    unsigned int* __restrict__ masks, float* __restrict__ invs) {
  const int idx = blockIdx.x * 256 + threadIdx.x;   // b*Q + q
  if (idx >= NQ_) return;
  const int b = idx >> 11;
  const float rx = refs[(size_t)idx * 3 + 0];
  const float ry = refs[(size_t)idx * 3 + 1];
  const float rz = refs[(size_t)idx * 3 + 2];
  unsigned int mask = 0;
  const size_t base = (size_t)idx * 48;
  for (int v = 0; v < V_; ++v) {
    const float* E = extr + ((size_t)b * V_ + v) * 16;
    const float* K = intr + ((size_t)b * V_ + v) * 9;
    for (int kp = 0; kp < KP_; ++kp) {
      const float kx = (kp == 1) ? RADIUS_ : ((kp == 3) ? -RADIUS_ : 0.f);
      const float ky = (kp == 2) ? RADIUS_ : 0.f;
      const float px = rx + kx, py = ry + ky, pz = rz;
      const float cx = E[0] * px + E[1] * py + E[2]  * pz + E[3];
      const float cy = E[4] * px + E[5] * py + E[6]  * pz + E[7];
      const float cz = E[8] * px + E[9] * py + E[10] * pz + E[11];
      const float uu = K[0] * cx + K[1] * cy + K[2] * cz;
      const float vv = K[3] * cx + K[4] * cy + K[5] * cz;
      const float ww = K[6] * cx + K[7] * cy + K[8] * cz;
      const float zc = fmaxf(ww, 1e-5f);
      const int s = v * KP_ + kp;
      xy[base + 2 * s]     = uu / zc;
      xy[base + 2 * s + 1] = vv / zc;
      if (ww > 0.f) mask |= (1u << s);
    }
  }
  masks[idx] = mask;
  invs[idx] = 0.5f / fmaxf((float)__popc(mask), 1.0f);
}

// ---------------------------------------------------------------------------
// Transpose CHW f32 -> HWC bf16, both levels in one launch.
// ---------------------------------------------------------------------------
__global__ __launch_bounds__(256) void transpose_bf16(
    const float* __restrict__ f0, const float* __restrict__ f1,
    unsigned short* __restrict__ f0t, unsigned short* __restrict__ f1t) {
  __shared__ float tile[64][69];
  int bx = blockIdx.x;
  const float* src; unsigned short* dst; int HW, bv, ptile;
  if (bx < T0_TILES_) {
    src = f0; dst = f0t; HW = HW0_;
    bv = bx / (HW0_ / 64); ptile = bx % (HW0_ / 64);
  } else {
    bx -= T0_TILES_;
    src = f1; dst = f1t; HW = HW1_;
    bv = bx / (HW1_ / 64); ptile = bx % (HW1_ / 64);
  }
  const int p0 = ptile * 64;
  const int ct0 = blockIdx.y * 64;
  const size_t sbase = (size_t)bv * C_ * HW;
  const size_t dbase = (size_t)bv * HW * C_;
  const int tid = threadIdx.x;

  {  // read-in: coalesced f32x4 along HW
    const int px4 = (tid & 15) * 4;
    const int crow = tid >> 4;      // 0..15
    for (int j = 0; j < 64; j += 16) {
      const f4 v = __builtin_nontemporal_load(
          reinterpret_cast<const f4*>(
              src + sbase + (size_t)(ct0 + crow + j) * HW + p0 + px4));
      tile[crow + j][px4 + 0] = v.x;
      tile[crow + j][px4 + 1] = v.y;
      tile[crow + j][px4 + 2] = v.z;
      tile[crow + j][px4 + 3] = v.w;
    }
  }
  __syncthreads();
  {  // write-out: us8 (16B) coalesced along C
    const int cx8 = (tid & 7) * 8;
    const int prow = tid >> 3;      // 0..31
    for (int j = 0; j < 64; j += 32) {
      us8 o;
      #pragma unroll
      for (int k = 0; k < 8; ++k) o[k] = f2bf(tile[cx8 + k][prow + j]);
      *reinterpret_cast<us8*>(
          dst + dbase + (size_t)(p0 + prow + j) * C_ + ct0 + cx8) = o;
    }
  }
}

// ---------------------------------------------------------------------------
// Level-1 sampler helper (kept branchy: ~90% of samples are OOB for L1, and
// the skip condition is wave-uniform on scalar data -> cheap s_cbranch).
// ---------------------------------------------------------------------------
__device__ __forceinline__ void sample_level_skip(
    const unsigned short* __restrict__ base, const int W, const int H,
    const float x0f, const float y0f,
    const float wx0, const float wx1, const float wy0, const float wy1,
    const int half, float acc[8]) {
  const float Wm1 = (float)(W - 1), Hm1 = (float)(H - 1);
  const float x1f = x0f + 1.f, y1f = y0f + 1.f;
  const bool bx0 = (x0f >= 0.f) && (x0f <= Wm1);
  const bool bx1 = (x1f >= 0.f) && (x1f <= Wm1);
  const bool by0 = (y0f >= 0.f) && (y0f <= Hm1);
  const bool by1 = (y1f >= 0.f) && (y1f <= Hm1);
  if (!((bx0 || bx1) && (by0 || by1))) return;
  const int xi0 = (int)fminf(fmaxf(x0f, 0.f), Wm1);
  const int xi1 = (int)fminf(fmaxf(x1f, 0.f), Wm1);
  const int xh = half ? xi1 : xi0;
  const float wxh = half ? (bx1 ? wx1 : 0.f) : (bx0 ? wx0 : 0.f);
  if (by0) {
    const int yi0 = (int)fminf(fmaxf(y0f, 0.f), Hm1);
    const us8 u = *reinterpret_cast<const us8*>(base + (size_t)(yi0 * W + xh) * C_);
    const float w = wxh * wy0;
    #pragma unroll
    for (int k = 0; k < 8; ++k) acc[k] = fmaf(w, bf2f(u[k]), acc[k]);
  }
  if (by1) {
    const int yi1 = (int)fminf(fmaxf(y1f, 0.f), Hm1);
    const us8 u = *reinterpret_cast<const us8*>(base + (size_t)(yi1 * W + xh) * C_);
    const float w = wxh * wy1;
    #pragma unroll
    for (int k = 0; k < 8; ++k) acc[k] = fmaf(w, bf2f(u[k]), acc[k]);
  }
}

// ---------------------------------------------------------------------------
// Sampler: wave = one query; lanes = 2 x-halves x 32 ch-lanes (8ch as us8).
// L0 gathers are branch-free (weights zeroed when OOB/invalid) so all 48
// row-loads pipeline; uniform metadata goes through the scalar path.
// ---------------------------------------------------------------------------
__global__ __launch_bounds__(256) void sampler_bf16(
    const unsigned short* __restrict__ f0t,   // [B,V,HW0,C] bf16
    const unsigned short* __restrict__ f1t,   // [B,V,HW1,C] bf16
    const float* __restrict__ xy,             // [NQ,24,2]
    const unsigned int* __restrict__ masks, const float* __restrict__ invs,
    float* __restrict__ out) {
  const int tid = threadIdx.x;
  const int wave = __builtin_amdgcn_readfirstlane(tid >> 6);   // wave-uniform
  const int lane = tid & 63;
  const int half = lane >> 5;
  const int cidx = lane & 31;      // 8 channels: 8*cidx .. 8*cidx+7
  const int idx = blockIdx.x * 4 + wave;   // b*Q + q  (SGPR)
  const int b = idx >> 11;

  const unsigned int mask = masks[idx];
  const float inv = invs[idx];
  const float* pxy = xy + (size_t)idx * 48;
  const int ce = cidx * 8;

  const unsigned short* F0 = f0t + (size_t)b * V_ * HW0_ * C_ + ce;
  const unsigned short* F1 = f1t + (size_t)b * V_ * HW1_ * C_ + ce;

  float acc[8] = {0.f, 0.f, 0.f, 0.f, 0.f, 0.f, 0.f, 0.f};

  #pragma unroll
  for (int s = 0; s < 24; ++s) {
    const bool valid = (mask >> s) & 1u;
    float x = pxy[2 * s], y = pxy[2 * s + 1];
    if (!valid) { x = 0.f; y = 0.f; }          // sanitize possible NaN/inf
    const float fvalid = valid ? 1.f : 0.f;
    const float x0f = floorf(x), y0f = floorf(y);
    const float wx1 = x - x0f, wy1 = y - y0f;
    const float wx0 = 1.f - wx1, wy0 = 1.f - wy1;
    const int v = s >> 2;

    // ---- level 0: branch-free ----
    {
      const float Wm1 = (float)(W0_ - 1), Hm1 = (float)(H0_ - 1);
      const float xhf = half ? (x0f + 1.f) : x0f;
      const float bx = (xhf >= 0.f && xhf <= Wm1) ? 1.f : 0.f;
      const float by0 = (y0f >= 0.f && y0f <= Hm1) ? 1.f : 0.f;
      const float by1 = (y0f + 1.f >= 0.f && y0f + 1.f <= Hm1) ? 1.f : 0.f;
      const float wxh = (half ? wx1 : wx0) * bx * fvalid;
      const int xh  = (int)fminf(fmaxf(xhf, 0.f), Wm1);
      const int yi0 = (int)fminf(fmaxf(y0f, 0.f), Hm1);
      const int yi1 = (int)fminf(fmaxf(y0f + 1.f, 0.f), Hm1);
      const float w0 = wxh * wy0 * by0;
      const float w1 = wxh * wy1 * by1;
      const unsigned short* Fv = F0 + (size_t)v * HW0_ * C_;
      const us8 u0 = *reinterpret_cast<const us8*>(Fv + (size_t)(yi0 * W0_ + xh) * C_);
      const us8 u1 = *reinterpret_cast<const us8*>(Fv + (size_t)(yi1 * W0_ + xh) * C_);
      #pragma unroll
      for (int k = 0; k < 8; ++k) {
        acc[k] = fmaf(w0, bf2f(u0[k]), acc[k]);
        acc[k] = fmaf(w1, bf2f(u1[k]), acc[k]);
      }
    }

    // ---- level 1: uniform skip (mostly OOB) ----
    sample_level_skip(F1 + (size_t)v * HW1_ * C_, W1_, H1_,
                      x0f, y0f, wx0 * fvalid, wx1 * fvalid, wy0, wy1,
                      half, acc);
  }

  // cross-half reduce: lane i and i+32 hold the same 8 channels
  #pragma unroll
  for (int k = 0; k < 8; ++k) acc[k] += __shfl_xor(acc[k], 32);

  // store: half 0 writes ch [8c,8c+4), half 1 writes [8c+4,8c+8)
  f4 o;
  const int ko = half * 4;
  o.x = acc[ko + 0] * inv;
  o.y = acc[ko + 1] * inv;
  o.z = acc[ko + 2] * inv;
  o.w = acc[ko + 3] * inv;
  __builtin_nontemporal_store(
      o, reinterpret_cast<f4*>(out + (size_t)idx * C_ + ce + ko));
}

// ---------------------------------------------------------------------------
// Fallback: direct gather from [B,V,C,H,W] (used only if workspace too small)
// ---------------------------------------------------------------------------
__device__ __forceinline__ float bilinear_scalar(
    const float* __restrict__ fm, const int W, const int H,
    const float x, const float y) {
  const float x0f = floorf(x), y0f = floorf(y);
  const float wx1 = x - x0f, wy1 = y - y0f;
  const float wx0 = 1.f - wx1, wy0 = 1.f - wy1;
  const float x1f = x0f + 1.f, y1f = y0f + 1.f;
  const float Wm1 = (float)(W - 1), Hm1 = (float)(H - 1);
  const bool bx0 = (x0f >= 0.f) && (x0f <= Wm1);
  const bool bx1 = (x1f >= 0.f) && (x1f <= Wm1);
  const bool by0 = (y0f >= 0.f) && (y0f <= Hm1);
  const bool by1 = (y1f >= 0.f) && (y1f <= Hm1);
  if (!((bx0 || bx1) && (by0 || by1))) return 0.f;
  const int xi0 = (int)fminf(fmaxf(x0f, 0.f), Wm1);
  const int xi1 = (int)fminf(fmaxf(x1f, 0.f), Wm1);
  const int yi0 = (int)fminf(fmaxf(y0f, 0.f), Hm1);
  const int yi1 = (int)fminf(fmaxf(y1f, 0.f), Hm1);
  float r = 0.f;
  if (bx0 && by0) r = fmaf(wx0 * wy0, fm[yi0 * W + xi0], r);
  if (bx1 && by0) r = fmaf(wx1 * wy0, fm[yi0 * W + xi1], r);
  if (bx0 && by1) r = fmaf(wx0 * wy1, fm[yi1 * W + xi0], r);
  if (bx1 && by1) r = fmaf(wx1 * wy1, fm[yi1 * W + xi1], r);
  return r;
}

__global__ __launch_bounds__(256) void sampler_direct(
    const float* __restrict__ f0, const float* __restrict__ f1,
    const float* __restrict__ refs, const float* __restrict__ intr,
    const float* __restrict__ extr, float* __restrict__ out) {
  __shared__ float sx[24], sy[24], scnt;
  __shared__ unsigned int smask;
  const int tid = threadIdx.x;
  const int b = blockIdx.y, q = blockIdx.x;
  bool zvalid = false;
  if (tid < 24) {
    const int v = tid >> 2, kp = tid & 3;
    const float kx = (kp == 1) ? RADIUS_ : ((kp == 3) ? -RADIUS_ : 0.f);
    const float ky = (kp == 2) ? RADIUS_ : 0.f;
    const float rx = refs[((size_t)b * Q_ + q) * 3 + 0];
    const float ry = refs[((size_t)b * Q_ + q) * 3 + 1];
    const float rz = refs[((size_t)b * Q_ + q) * 3 + 2];
    const float px = rx + kx, py = ry + ky, pz = rz;
    const float* E = extr + ((size_t)b * V_ + v) * 16;
    const float cx = E[0] * px + E[1] * py + E[2]  * pz + E[3];
    const float cy = E[4] * px + E[5] * py + E[6]  * pz + E[7];
    const float cz = E[8] * px + E[9] * py + E[10] * pz + E[11];
    const float* K = intr + ((size_t)b * V_ + v) * 9;
    const float uu = K[0] * cx + K[1] * cy + K[2] * cz;
    const float vv = K[3] * cx + K[4] * cy + K[5] * cz;
    const float ww = K[6] * cx + K[7] * cy + K[8] * cz;
    const float zc = fmaxf(ww, 1e-5f);
    sx[tid] = uu / zc;
    sy[tid] = vv / zc;
    zvalid = (ww > 0.f);
  }
  const unsigned long long m = __ballot(zvalid);
  if (tid == 0) {
    const unsigned int mm = (unsigned int)(m & 0xFFFFFFULL);
    smask = mm;
    scnt = fmaxf((float)__popc(mm), 1.0f);
  }
  __syncthreads();
  const unsigned int mask = smask;
  const float cnt = scnt;
  const int c = tid;
  float a0 = 0.f, a1 = 0.f;
  for (int s = 0; s < 24; ++s) {
    if (!((mask >> s) & 1u)) continue;
    const float x = sx[s], y = sy[s];
    const int v = s >> 2;
    const size_t bv = (size_t)b * V_ + v;
    a0 += bilinear_scalar(f0 + (bv * C_ + c) * (size_t)HW0_, W0_, H0_, x, y);
    a1 += bilinear_scalar(f1 + (bv * C_ + c) * (size_t)HW1_, W1_, H1_, x, y);
  }
  out[((size_t)b * Q_ + q) * C_ + c] = (a0 + a1) * 0.5f / cnt;
}

// ---------------------------------------------------------------------------
extern "C" void kernel_launch(void* const* d_in, const int* in_sizes, int n_in,
                              void* d_out, int out_size, void* d_ws, size_t ws_size,
                              hipStream_t stream) {
  const float* feat0 = (const float*)d_in[0];
  const float* feat1 = (const float*)d_in[1];
  const float* refs  = (const float*)d_in[2];
  const float* intr  = (const float*)d_in[3];
  const float* extr  = (const float*)d_in[4];
  float* out = (float*)d_out;

  const size_t need = F0_ELEMS * 2 + F1_ELEMS * 2          // bf16 copies
                    + ((size_t)NQ_ * 48 + 2 * NQ_) * 4;    // xy + mask + inv

  if (ws_size >= need) {
    unsigned short* f0t = (unsigned short*)d_ws;
    unsigned short* f1t = f0t + F0_ELEMS;
    float* xy = (float*)(f1t + F1_ELEMS);
    unsigned int* masks = (unsigned int*)(xy + (size_t)NQ_ * 48);
    float* invs = (float*)(masks + NQ_);

    proj_kernel<<<NQ_ / 256, 256, 0, stream>>>(refs, intr, extr, xy, masks, invs);
    transpose_bf16<<<dim3(T0_TILES_ + T1_TILES_, C_ / 64), 256, 0, stream>>>(
        feat0, feat1, f0t, f1t);
    sampler_bf16<<<dim3(NQ_ / 4), 256, 0, stream>>>(
        f0t, f1t, xy, masks, invs, out);
  } else {
    sampler_direct<<<dim3(Q_, B_), 256, 0, stream>>>(
        feat0, feat1, refs, intr, extr, out);
  }
}